// Round 10
// baseline (2024.218 us; speedup 1.0000x reference)
//
#include <hip/hip_runtime.h>

// V=10000, R=8192, D=1024, B=1024, L=64, M=65536
// R10 = R9 (1293 us) + two LDS-pipe fixes in all GEMMs:
//  (1) row pad 32->40 elems (80 B = 5x16B): quarter-wave b128 frag reads and
//      staging writes spread over all 32 banks (was 8 -> SQ_LDS_BANK_CONFLICT
//      3.36e7/dispatch ~ 12% of k_mlp cycles). Staging map row=tid&63,
//      chunk=tid>>6 keeps writes uniform.
//  (2) double-buffered K-loop with ONE barrier/iter (read buf p, write buf
//      p^1, barrier). Keeps R7's VGPR prefetch (global->VGPR loads are NOT
//      drained at s_barrier, unlike gl16 - the R8 lesson). k_step also BK=64.
#define D_DIM   1024
#define L_SEQ   64
#define B_BATCH 1024
#define M_NODES 65536
#define R_RULES 8192
#define V_VOCAB 10000
#define LDA     40   // padded row stride (elems) for 128-row tiles, BK=32
#define LDK     72   // padded row stride (elems) for 64-row tiles, BK=64

typedef unsigned short bf16_t;
typedef __attribute__((ext_vector_type(8))) short s8v;   // 8 bf16 (MFMA A/B frag)
typedef __attribute__((ext_vector_type(4))) float f4v;   // MFMA C/D frag

static __device__ __forceinline__ float bf2f(unsigned short u) {
    union { unsigned int i; float f; } v; v.i = ((unsigned int)u) << 16; return v.f;
}
static __device__ __forceinline__ unsigned short f2bf(float f) {  // RNE
    union { float f; unsigned int i; } v; v.f = f;
    return (unsigned short)((v.i + 0x7FFFu + ((v.i >> 16) & 1u)) >> 16);
}
static __device__ __forceinline__ float fast_tanh(float x) {
    float xc = fminf(fmaxf(x, -15.f), 15.f);
    float t  = __expf(2.f * xc);
    return (t - 1.f) * __builtin_amdgcn_rcpf(t + 1.f);
}

static __device__ __forceinline__ f4v mfma16(s8v a, s8v b, f4v c) {
    return __builtin_amdgcn_mfma_f32_16x16x32_bf16(a, b, c, 0, 0, 0);
}

// ---------------------------------------------------------------------------
__global__ __launch_bounds__(256) void k_cvt_emb(
    const float* __restrict__ emb, bf16_t* __restrict__ embB)
{
    size_t i = ((size_t)blockIdx.x * 256 + threadIdx.x) * 8;
    f4v x0 = *(const f4v*)&emb[i];
    f4v x1 = *(const f4v*)&emb[i + 4];
    s8v o;
    o[0] = (short)f2bf(x0.x); o[1] = (short)f2bf(x0.y);
    o[2] = (short)f2bf(x0.z); o[3] = (short)f2bf(x0.w);
    o[4] = (short)f2bf(x1.x); o[5] = (short)f2bf(x1.y);
    o[6] = (short)f2bf(x1.z); o[7] = (short)f2bf(x1.w);
    *(s8v*)&embB[i] = o;
}

__global__ __launch_bounds__(256) void k_transcvt(
    const float* __restrict__ src, bf16_t* __restrict__ dst, int K, int N)
{
    __shared__ float s[32][33];
    int n0 = blockIdx.x * 32, k0 = blockIdx.y * 32;
    int tx = threadIdx.x, ty = threadIdx.y;  // (32,8)
#pragma unroll
    for (int i = 0; i < 4; ++i)
        s[ty + i * 8][tx] = src[(size_t)(k0 + ty + i * 8) * N + n0 + tx];
    __syncthreads();
#pragma unroll
    for (int i = 0; i < 4; ++i)
        dst[(size_t)(n0 + ty + i * 8) * K + k0 + tx] = f2bf(s[tx][ty + i * 8]);
}

__global__ __launch_bounds__(256) void k_cvt_h0(
    const float* __restrict__ h0, bf16_t* __restrict__ h0b)
{
    for (int u = threadIdx.x; u < D_DIM; u += 256) h0b[u] = f2bf(h0[u]);
}

// ---------------------------------------------------------------------------
// k_xw_mfma: XE[n,:] = bf16(embB[tokens[n],:] @ Wxh + bh)
// 128x128, BK=32, dbuf single-barrier, pad-40, XCD swizzle.
// ---------------------------------------------------------------------------
__global__ __launch_bounds__(256) void k_xw_mfma(
    const int* __restrict__ tokens, const bf16_t* __restrict__ embB,
    const bf16_t* __restrict__ WxhT, const float* __restrict__ bh,
    bf16_t* __restrict__ XE)
{
    __shared__ bf16_t As[2][128 * LDA];        // 2 x 10 KB
    __shared__ bf16_t Bs[2][128 * LDA];        // 2 x 10 KB
    __shared__ float  epi[4][16][68];          // 17.4 KB (per-wave private)

    const int bi  = blockIdx.x;
    const int xcd = bi & 7, j = bi >> 3;
    const int row0 = ((xcd << 6) + (j >> 3)) * 128;
    const int col0 = (j & 7) * 128;

    const int tid = threadIdx.x;
    const int w = tid >> 6, l = tid & 63;
    const int q = l >> 4, t16 = l & 15;
    const int wm = (w >> 1) * 64, wn = (w & 1) * 64;

    // staging map: row = tid&63 (+0/64), chunk = tid>>6 (8 elems)
    const int sr = tid & 63, sc = (tid >> 6) << 3;
    const bf16_t* arow[2];
#pragma unroll
    for (int r = 0; r < 2; ++r)
        arow[r] = embB + (size_t)tokens[row0 + sr + r * 64] * D_DIM + sc;
    const bf16_t* brow[2];
#pragma unroll
    for (int r = 0; r < 2; ++r)
        brow[r] = WxhT + (size_t)(col0 + sr + r * 64) * D_DIM + sc;

    f4v acc[4][4];
#pragma unroll
    for (int i = 0; i < 4; ++i)
#pragma unroll
        for (int jj = 0; jj < 4; ++jj) acc[i][jj] = (f4v)0.f;

    // prologue: stage k=0 into buf0, prefetch k=32
    s8v a0 = *(const s8v*)(arow[0]);
    s8v a1 = *(const s8v*)(arow[1]);
    s8v b0 = *(const s8v*)(brow[0]);
    s8v b1 = *(const s8v*)(brow[1]);
    *(s8v*)&As[0][sr * LDA + sc]        = a0;
    *(s8v*)&As[0][(sr + 64) * LDA + sc] = a1;
    *(s8v*)&Bs[0][sr * LDA + sc]        = b0;
    *(s8v*)&Bs[0][(sr + 64) * LDA + sc] = b1;
    a0 = *(const s8v*)(arow[0] + 32);
    a1 = *(const s8v*)(arow[1] + 32);
    b0 = *(const s8v*)(brow[0] + 32);
    b1 = *(const s8v*)(brow[1] + 32);
    __syncthreads();

    int p = 0;
    for (int k0 = 0; k0 < D_DIM; k0 += 32) {
        s8v af[4], bfr[4];
#pragma unroll
        for (int ti = 0; ti < 4; ++ti)
            af[ti] = *(const s8v*)&As[p][(wm + ti * 16 + t16) * LDA + q * 8];
#pragma unroll
        for (int tj = 0; tj < 4; ++tj)
            bfr[tj] = *(const s8v*)&Bs[p][(wn + tj * 16 + t16) * LDA + q * 8];
        if (k0 + 32 < D_DIM) {
            *(s8v*)&As[p ^ 1][sr * LDA + sc]        = a0;
            *(s8v*)&As[p ^ 1][(sr + 64) * LDA + sc] = a1;
            *(s8v*)&Bs[p ^ 1][sr * LDA + sc]        = b0;
            *(s8v*)&Bs[p ^ 1][(sr + 64) * LDA + sc] = b1;
            if (k0 + 64 < D_DIM) {
                a0 = *(const s8v*)(arow[0] + k0 + 64);
                a1 = *(const s8v*)(arow[1] + k0 + 64);
                b0 = *(const s8v*)(brow[0] + k0 + 64);
                b1 = *(const s8v*)(brow[1] + k0 + 64);
            }
        }
#pragma unroll
        for (int ti = 0; ti < 4; ++ti)
#pragma unroll
            for (int tj = 0; tj < 4; ++tj)
                acc[ti][tj] = mfma16(af[ti], bfr[tj], acc[ti][tj]);
        __syncthreads();
        p ^= 1;
    }

    // barrier-free per-wave epilogue (epi[w] wave-private)
    const int lr = l >> 2, c16 = (l & 3) * 16;
    f4v bias[4];
#pragma unroll
    for (int u = 0; u < 4; ++u)
        bias[u] = *(const f4v*)&bh[col0 + wn + c16 + u * 4];
#pragma unroll
    for (int ti = 0; ti < 4; ++ti) {
#pragma unroll
        for (int tj = 0; tj < 4; ++tj)
#pragma unroll
            for (int rg = 0; rg < 4; ++rg)
                epi[w][q * 4 + rg][tj * 16 + t16] = acc[ti][tj][rg];
        s8v o0, o1;
#pragma unroll
        for (int u = 0; u < 8; ++u) {
            o0[u] = (short)f2bf(epi[w][lr][c16 + u]     + bias[u >> 2][u & 3]);
            o1[u] = (short)f2bf(epi[w][lr][c16 + 8 + u] + bias[2 + (u >> 2)][u & 3]);
        }
        size_t orow = (size_t)(row0 + wm + ti * 16 + lr) * D_DIM + col0 + wn + c16;
        *(s8v*)&XE[orow]     = o0;
        *(s8v*)&XE[orow + 8] = o1;
    }
}

// ---------------------------------------------------------------------------
// k_step_mfma (x64): y = tanh(XE[b*L+t,:] + h_prev[b,:] @ Whh); XE[..] = bf16(y)
// 64x64 tile, 512 thr (8 waves), BK=64, dbuf single-barrier, pad-72.
// Wave (wr,wc)=(w>>2,w&3): rows wr*32+[0,32), cols wc*16+[0,16).
// ---------------------------------------------------------------------------
__global__ __launch_bounds__(512) void k_step_mfma(
    const bf16_t* __restrict__ Abase, int strideRow,
    const bf16_t* __restrict__ WhhT, bf16_t* __restrict__ XE, int t)
{
    __shared__ bf16_t As[2][64 * LDK];         // 2 x 9 KB
    __shared__ bf16_t Bs[2][64 * LDK];         // 2 x 9 KB
    __shared__ float  epi[8][16][20];          // 10.2 KB (per-wave private)

    const int tid = threadIdx.x;
    const int w = tid >> 6, l = tid & 63;
    const int q = l >> 4, t16 = l & 15;
    const int wr = w >> 2, wc = w & 3;
    const int row0 = blockIdx.x * 64, col0 = blockIdx.y * 64;

    // staging: row = tid&63, chunk = tid>>6 (0..7) * 8 elems  -> BK=64
    const int sr = tid & 63, sc = (tid >> 6) << 3;
    const bf16_t* asrc = Abase + (size_t)(row0 + sr) * strideRow + sc;
    const bf16_t* bsrc = WhhT + (size_t)(col0 + sr) * D_DIM + sc;

    f4v acc0 = (f4v)0.f, acc1 = (f4v)0.f;

    s8v rA = *(const s8v*)(asrc);
    s8v rB = *(const s8v*)(bsrc);
    *(s8v*)&As[0][sr * LDK + sc] = rA;
    *(s8v*)&Bs[0][sr * LDK + sc] = rB;
    rA = *(const s8v*)(asrc + 64);
    rB = *(const s8v*)(bsrc + 64);
    __syncthreads();

    int p = 0;
    for (int k0 = 0; k0 < D_DIM; k0 += 64) {
        s8v af0[2], af1[2], bf0, bf1;
#pragma unroll
        for (int ti = 0; ti < 2; ++ti) {
            af0[ti] = *(const s8v*)&As[p][(wr * 32 + ti * 16 + t16) * LDK + q * 8];
            af1[ti] = *(const s8v*)&As[p][(wr * 32 + ti * 16 + t16) * LDK + 32 + q * 8];
        }
        bf0 = *(const s8v*)&Bs[p][(wc * 16 + t16) * LDK + q * 8];
        bf1 = *(const s8v*)&Bs[p][(wc * 16 + t16) * LDK + 32 + q * 8];
        if (k0 + 64 < D_DIM) {
            *(s8v*)&As[p ^ 1][sr * LDK + sc] = rA;
            *(s8v*)&Bs[p ^ 1][sr * LDK + sc] = rB;
            if (k0 + 128 < D_DIM) {
                rA = *(const s8v*)(asrc + k0 + 128);
                rB = *(const s8v*)(bsrc + k0 + 128);
            }
        }
        acc0 = mfma16(af0[0], bf0, acc0);
        acc1 = mfma16(af0[1], bf0, acc1);
        acc0 = mfma16(af1[0], bf1, acc0);
        acc1 = mfma16(af1[1], bf1, acc1);
        __syncthreads();
        p ^= 1;
    }

    // per-wave epilogue, no barriers
    const int lr = l >> 2, c4 = (l & 3) * 4;
    f4v accs[2] = {acc0, acc1};
#pragma unroll
    for (int ti = 0; ti < 2; ++ti) {
#pragma unroll
        for (int rg = 0; rg < 4; ++rg)
            epi[w][q * 4 + rg][t16] = accs[ti][rg];
        f4v v = *(const f4v*)&epi[w][lr][c4];
        int b = row0 + wr * 32 + ti * 16 + lr;
        size_t xi = ((size_t)b * L_SEQ + t) * D_DIM + col0 + wc * 16 + c4;
        unsigned long long xr = *(const unsigned long long*)&XE[xi];
        unsigned long long ow = 0;
#pragma unroll
        for (int u = 0; u < 4; ++u) {
            unsigned short xu = (unsigned short)((xr >> (16 * u)) & 0xFFFF);
            unsigned short oo = f2bf(fast_tanh(bf2f(xu) + v[u]));
            ow |= ((unsigned long long)oo) << (16 * u);
        }
        *(unsigned long long*)&XE[xi] = ow;
    }
}

// ---------------------------------------------------------------------------
// k_mlp_mfma: h = tanh(concat(XE[i],XE[j]) @ W1 + b1) fused with rule-dot.
// 128x128, K=2048, BK=32, dbuf single-barrier, pad-40, XCD swizzle.
// ---------------------------------------------------------------------------
__global__ __launch_bounds__(256) void k_mlp_mfma(
    const int* __restrict__ i_idx, const int* __restrict__ j_idx,
    const bf16_t* __restrict__ XE, const bf16_t* __restrict__ W1T,
    const float* __restrict__ b1, const bf16_t* __restrict__ Wt2,
    const int* __restrict__ r_idx, float* __restrict__ partials)
{
    __shared__ bf16_t As[2][128 * LDA];        // 2 x 10 KB
    __shared__ bf16_t Bs[2][128 * LDA];        // 2 x 10 KB

    const int bi  = blockIdx.x;
    const int xcd = bi & 7, j = bi >> 3;
    const int rowTile = (xcd << 6) + (j >> 3);
    const int colTile = j & 7;
    const int row0 = rowTile * 128, col0 = colTile * 128;

    const int tid = threadIdx.x;
    const int w = tid >> 6, l = tid & 63;
    const int q = l >> 4, t16 = l & 15;
    const int wm = (w >> 1) * 64, wn = (w & 1) * 64;

    const int sr = tid & 63, sc = (tid >> 6) << 3;
    const bf16_t* pi[2]; const bf16_t* pj[2];
#pragma unroll
    for (int r = 0; r < 2; ++r) {
        int m = row0 + sr + r * 64;
        pi[r] = XE + (size_t)i_idx[m] * D_DIM + sc;
        pj[r] = XE + (size_t)j_idx[m] * D_DIM - D_DIM + sc;   // k in [1024,2048)
    }
    const bf16_t* brow[2];
#pragma unroll
    for (int r = 0; r < 2; ++r)
        brow[r] = W1T + (size_t)(col0 + sr + r * 64) * (2 * D_DIM) + sc;

    f4v acc[4][4];
#pragma unroll
    for (int i = 0; i < 4; ++i)
#pragma unroll
        for (int jj = 0; jj < 4; ++jj) acc[i][jj] = (f4v)0.f;

    // prologue
    s8v a0 = *(const s8v*)(pi[0]);
    s8v a1 = *(const s8v*)(pi[1]);
    s8v b0 = *(const s8v*)(brow[0]);
    s8v b1v = *(const s8v*)(brow[1]);
    *(s8v*)&As[0][sr * LDA + sc]        = a0;
    *(s8v*)&As[0][(sr + 64) * LDA + sc] = a1;
    *(s8v*)&Bs[0][sr * LDA + sc]        = b0;
    *(s8v*)&Bs[0][(sr + 64) * LDA + sc] = b1v;
    a0  = *(const s8v*)(pi[0] + 32);
    a1  = *(const s8v*)(pi[1] + 32);
    b0  = *(const s8v*)(brow[0] + 32);
    b1v = *(const s8v*)(brow[1] + 32);
    __syncthreads();

    int p = 0;
    for (int k0 = 0; k0 < 2 * D_DIM; k0 += 32) {
        s8v af[4], bfr[4];
#pragma unroll
        for (int ti = 0; ti < 4; ++ti)
            af[ti] = *(const s8v*)&As[p][(wm + ti * 16 + t16) * LDA + q * 8];
#pragma unroll
        for (int tj = 0; tj < 4; ++tj)
            bfr[tj] = *(const s8v*)&Bs[p][(wn + tj * 16 + t16) * LDA + q * 8];
        if (k0 + 32 < 2 * D_DIM) {
            *(s8v*)&As[p ^ 1][sr * LDA + sc]        = a0;
            *(s8v*)&As[p ^ 1][(sr + 64) * LDA + sc] = a1;
            *(s8v*)&Bs[p ^ 1][sr * LDA + sc]        = b0;
            *(s8v*)&Bs[p ^ 1][(sr + 64) * LDA + sc] = b1v;
            if (k0 + 64 < 2 * D_DIM) {
                int kn = k0 + 64;
                a0  = *(const s8v*)(((kn < D_DIM) ? pi[0] : pj[0]) + kn);
                a1  = *(const s8v*)(((kn < D_DIM) ? pi[1] : pj[1]) + kn);
                b0  = *(const s8v*)(brow[0] + kn);
                b1v = *(const s8v*)(brow[1] + kn);
            }
        }
#pragma unroll
        for (int ti = 0; ti < 4; ++ti)
#pragma unroll
            for (int tj = 0; tj < 4; ++tj)
                acc[ti][tj] = mfma16(af[ti], bfr[tj], acc[ti][tj]);
        __syncthreads();
        p ^= 1;
    }

    // fused epilogue in C-layout: fast_tanh, dot with gathered rule row, 16-lane reduce
    const int cb = colTile * 2 + (w & 1);
#pragma unroll
    for (int ti = 0; ti < 4; ++ti) {
#pragma unroll
        for (int rg = 0; rg < 4; ++rg) {
            int m = row0 + wm + ti * 16 + q * 4 + rg;
            int r = r_idx[m];
            const bf16_t* wrow = Wt2 + (size_t)r * D_DIM + col0 + wn + t16;
            float pd = 0.f;
#pragma unroll
            for (int tj = 0; tj < 4; ++tj) {
                int col = col0 + wn + tj * 16 + t16;
                float h = fast_tanh(acc[ti][tj][rg] + b1[col]);
                pd += h * bf2f(wrow[tj * 16]);
            }
            pd += __shfl_xor(pd, 1);
            pd += __shfl_xor(pd, 2);
            pd += __shfl_xor(pd, 4);
            pd += __shfl_xor(pd, 8);
            if (t16 == 0)
                partials[(size_t)cb * M_NODES + m] = pd;
        }
    }
}

// ---------------------------------------------------------------------------
__global__ __launch_bounds__(256) void k_reduce(
    const float* __restrict__ partials, const int* __restrict__ r_idx,
    const float* __restrict__ b2, float* __restrict__ out)
{
    int m = blockIdx.x * 256 + threadIdx.x;
    float s = 0.f;
#pragma unroll
    for (int cb = 0; cb < 16; ++cb)
        s += partials[(size_t)cb * M_NODES + m];
    out[m] = s + b2[r_idx[m]];
}

// ---------------------------------------------------------------------------
extern "C" void kernel_launch(void* const* d_in, const int* in_sizes, int n_in,
                              void* d_out, int out_size, void* d_ws, size_t ws_size,
                              hipStream_t stream) {
    const int*   tokens = (const int*)  d_in[0];
    const int*   i_idx  = (const int*)  d_in[1];
    const int*   j_idx  = (const int*)  d_in[2];
    const int*   r_idx  = (const int*)  d_in[3];
    const float* emb    = (const float*)d_in[4];
    const float* Wxh    = (const float*)d_in[5];
    const float* Whh    = (const float*)d_in[6];
    const float* bh     = (const float*)d_in[7];
    const float* h0     = (const float*)d_in[8];
    const float* W1     = (const float*)d_in[9];
    const float* b1     = (const float*)d_in[10];
    const float* W2     = (const float*)d_in[11];
    const float* b2     = (const float*)d_in[12];
    float* out = (float*)d_out;

    // Workspace (~156 MiB). embB (20 MiB) aliases WhhT/W1T/Wt2 (22 MiB):
    // embB dead after k_xw_mfma; those conversions run after it.
    bf16_t* XE   = (bf16_t*)d_ws;                        // [B*L][D]  128 MiB
    bf16_t* WxhT = XE   + (size_t)M_NODES * D_DIM;       // [D][D]      2 MiB
    bf16_t* WhhT = WxhT + (size_t)D_DIM * D_DIM;         // [D][D]      2 MiB
    bf16_t* W1T  = WhhT + (size_t)D_DIM * D_DIM;         // [D][2D]     4 MiB
    bf16_t* Wt2  = W1T  + (size_t)2 * D_DIM * D_DIM;     // [R][D]     16 MiB
    bf16_t* embB = WhhT;                                 // [V][D]     20 MiB (alias)
    bf16_t* h0b  = Wt2  + (size_t)R_RULES * D_DIM;       // [D] (pad 2048)
    float*  par  = (float*)(h0b + 2048);                 // [16][M]     4 MiB

    // Phase 1: emb->bf16, Wxh, h0
    k_cvt_emb<<<V_VOCAB * D_DIM / 2048, 256, 0, stream>>>(emb, embB);
    k_transcvt<<<dim3(D_DIM / 32, D_DIM / 32), dim3(32, 8), 0, stream>>>(Wxh, WxhT, D_DIM, D_DIM);
    k_cvt_h0<<<1, 256, 0, stream>>>(h0, h0b);

    // Phase 2: XE = bf16(embB[tokens] @ Wxh + bh)   (last reader of embB)
    k_xw_mfma<<<4096, 256, 0, stream>>>(tokens, embB, WxhT, bh, XE);

    // Phase 3: remaining weight conversions (overwrite embB region)
    k_transcvt<<<dim3(D_DIM / 32, D_DIM / 32), dim3(32, 8), 0, stream>>>(Whh, WhhT, D_DIM, D_DIM);
    k_transcvt<<<dim3(D_DIM / 32, 2 * D_DIM / 32), dim3(32, 8), 0, stream>>>(W1, W1T, 2 * D_DIM, D_DIM);
    k_transcvt<<<dim3(R_RULES / 32, D_DIM / 32), dim3(32, 8), 0, stream>>>(W2, Wt2, D_DIM, R_RULES);

    // Phase 4: 64 sequential RNN steps (in-place on XE)
    for (int t = 0; t < L_SEQ; ++t) {
        const bf16_t* Abase = (t == 0) ? h0b : (XE + (size_t)(t - 1) * D_DIM);
        int strideRow       = (t == 0) ? 0   : L_SEQ * D_DIM;
        k_step_mfma<<<dim3(B_BATCH / 64, D_DIM / 64), 512, 0, stream>>>(
            Abase, strideRow, WhhT, XE, t);
    }

    // Phase 5: MLP + fused rule-dot partials
    k_mlp_mfma<<<4096, 256, 0, stream>>>(
        i_idx, j_idx, XE, W1T, b1, Wt2, r_idx, par);

    // Phase 6: deterministic reduce + b2
    k_reduce<<<M_NODES / 256, 256, 0, stream>>>(par, r_idx, b2, out);
}

// Round 11
// 1313.341 us; speedup vs baseline: 1.5413x; 1.5413x over previous
//
#include <hip/hip_runtime.h>

// V=10000, R=8192, D=1024, B=1024, L=64, M=65536
// R11 = R9 (1293 us, best) + ONE change: LDS row stride 32 -> 40 elems
// (80 B = 5x16B, keeps b128 align; frag-read quarter-waves span 8 bank-group
// offsets -> 2-way aliasing = free, vs 8-way at stride 32).
// R10 lessons burned in: (a) the staging thread->data map must keep 4 lanes
// per 64B row segment for global coalescing — R10's 64-rows-per-wave map
// scattered 64 cache lines per load instr and doubled total time; (b)
// SQ_LDS_BANK_CONFLICT reads exactly 2^25 every round = saturated artifact,
// do not trust it; (c) dbuf single-barrier showed no isolated win — keep R9's
// two-barrier loop.
#define D_DIM   1024
#define L_SEQ   64
#define B_BATCH 1024
#define M_NODES 65536
#define R_RULES 8192
#define V_VOCAB 10000
#define LDA     40   // padded LDS row stride (elems), BK=32 tiles

typedef unsigned short bf16_t;
typedef __attribute__((ext_vector_type(8))) short s8v;   // 8 bf16 (MFMA A/B frag)
typedef __attribute__((ext_vector_type(4))) short s4v;   // 4 bf16
typedef __attribute__((ext_vector_type(4))) float f4v;   // MFMA C/D frag

static __device__ __forceinline__ float bf2f(unsigned short u) {
    union { unsigned int i; float f; } v; v.i = ((unsigned int)u) << 16; return v.f;
}
static __device__ __forceinline__ unsigned short f2bf(float f) {  // RNE
    union { float f; unsigned int i; } v; v.f = f;
    return (unsigned short)((v.i + 0x7FFFu + ((v.i >> 16) & 1u)) >> 16);
}
static __device__ __forceinline__ float fast_tanh(float x) {
    float xc = fminf(fmaxf(x, -15.f), 15.f);
    float t  = __expf(2.f * xc);
    return (t - 1.f) * __builtin_amdgcn_rcpf(t + 1.f);
}

static __device__ __forceinline__ f4v mfma16(s8v a, s8v b, f4v c) {
    return __builtin_amdgcn_mfma_f32_16x16x32_bf16(a, b, c, 0, 0, 0);
}

// ---------------------------------------------------------------------------
__global__ __launch_bounds__(256) void k_cvt_emb(
    const float* __restrict__ emb, bf16_t* __restrict__ embB)
{
    size_t i = ((size_t)blockIdx.x * 256 + threadIdx.x) * 8;
    f4v x0 = *(const f4v*)&emb[i];
    f4v x1 = *(const f4v*)&emb[i + 4];
    s8v o;
    o[0] = (short)f2bf(x0.x); o[1] = (short)f2bf(x0.y);
    o[2] = (short)f2bf(x0.z); o[3] = (short)f2bf(x0.w);
    o[4] = (short)f2bf(x1.x); o[5] = (short)f2bf(x1.y);
    o[6] = (short)f2bf(x1.z); o[7] = (short)f2bf(x1.w);
    *(s8v*)&embB[i] = o;
}

__global__ __launch_bounds__(256) void k_transcvt(
    const float* __restrict__ src, bf16_t* __restrict__ dst, int K, int N)
{
    __shared__ float s[32][33];
    int n0 = blockIdx.x * 32, k0 = blockIdx.y * 32;
    int tx = threadIdx.x, ty = threadIdx.y;  // (32,8)
#pragma unroll
    for (int i = 0; i < 4; ++i)
        s[ty + i * 8][tx] = src[(size_t)(k0 + ty + i * 8) * N + n0 + tx];
    __syncthreads();
#pragma unroll
    for (int i = 0; i < 4; ++i)
        dst[(size_t)(n0 + ty + i * 8) * K + k0 + tx] = f2bf(s[tx][ty + i * 8]);
}

__global__ __launch_bounds__(256) void k_cvt_h0(
    const float* __restrict__ h0, bf16_t* __restrict__ h0b)
{
    for (int u = threadIdx.x; u < D_DIM; u += 256) h0b[u] = f2bf(h0[u]);
}

// ---------------------------------------------------------------------------
// k_xw_mfma: XE[n,:] = bf16(embB[tokens[n],:] @ Wxh + bh)
// 128x128, BK=32, R9 two-barrier loop + VGPR prefetch, pad-40, XCD swizzle.
// ---------------------------------------------------------------------------
__global__ __launch_bounds__(256) void k_xw_mfma(
    const int* __restrict__ tokens, const bf16_t* __restrict__ embB,
    const bf16_t* __restrict__ WxhT, const float* __restrict__ bh,
    bf16_t* __restrict__ XE)
{
    __shared__ bf16_t As[128 * LDA];           // 10 KB
    __shared__ bf16_t Bs[128 * LDA];           // 10 KB
    __shared__ float  epi[4][16][68];          // 17.4 KB (per-wave private)

    const int bi  = blockIdx.x;
    const int xcd = bi & 7, j = bi >> 3;
    const int row0 = ((xcd << 6) + (j >> 3)) * 128;
    const int col0 = (j & 7) * 128;

    const int tid = threadIdx.x;
    const int w = tid >> 6, l = tid & 63;
    const int q = l >> 4, t16 = l & 15;
    const int wm = (w >> 1) * 64, wn = (w & 1) * 64;

    // R9 coalesced staging map: 4 lanes cover 64 B of one row
    const int rr = tid >> 2, cc = (tid & 3) << 3;
    const bf16_t* arow[2];
#pragma unroll
    for (int r = 0; r < 2; ++r)
        arow[r] = embB + (size_t)tokens[row0 + rr + r * 64] * D_DIM + cc;
    const bf16_t* brow[2];
#pragma unroll
    for (int r = 0; r < 2; ++r)
        brow[r] = WxhT + (size_t)(col0 + rr + r * 64) * D_DIM + cc;

    f4v acc[4][4];
#pragma unroll
    for (int i = 0; i < 4; ++i)
#pragma unroll
        for (int jj = 0; jj < 4; ++jj) acc[i][jj] = (f4v)0.f;

    // prefetch k=0
    s8v a0 = *(const s8v*)(arow[0]);
    s8v a1 = *(const s8v*)(arow[1]);
    s8v b0 = *(const s8v*)(brow[0]);
    s8v b1 = *(const s8v*)(brow[1]);

    for (int k0 = 0; k0 < D_DIM; k0 += 32) {
        __syncthreads();                       // prev iter frag reads done
        *(s8v*)&As[rr * LDA + cc]        = a0;
        *(s8v*)&As[(rr + 64) * LDA + cc] = a1;
        *(s8v*)&Bs[rr * LDA + cc]        = b0;
        *(s8v*)&Bs[(rr + 64) * LDA + cc] = b1;
        int kn = k0 + 32;
        if (kn < D_DIM) {                      // issue next loads early
            a0 = *(const s8v*)(arow[0] + kn);
            a1 = *(const s8v*)(arow[1] + kn);
            b0 = *(const s8v*)(brow[0] + kn);
            b1 = *(const s8v*)(brow[1] + kn);
        }
        __syncthreads();
        s8v af[4], bfr[4];
#pragma unroll
        for (int ti = 0; ti < 4; ++ti)
            af[ti] = *(const s8v*)&As[(wm + ti * 16 + t16) * LDA + q * 8];
#pragma unroll
        for (int tj = 0; tj < 4; ++tj)
            bfr[tj] = *(const s8v*)&Bs[(wn + tj * 16 + t16) * LDA + q * 8];
#pragma unroll
        for (int ti = 0; ti < 4; ++ti)
#pragma unroll
            for (int tj = 0; tj < 4; ++tj)
                acc[ti][tj] = mfma16(af[ti], bfr[tj], acc[ti][tj]);
    }

    // barrier-free per-wave epilogue (epi[w] wave-private)
    const int lr = l >> 2, c16 = (l & 3) * 16;
    f4v bias[4];
#pragma unroll
    for (int u = 0; u < 4; ++u)
        bias[u] = *(const f4v*)&bh[col0 + wn + c16 + u * 4];
#pragma unroll
    for (int ti = 0; ti < 4; ++ti) {
#pragma unroll
        for (int tj = 0; tj < 4; ++tj)
#pragma unroll
            for (int rg = 0; rg < 4; ++rg)
                epi[w][q * 4 + rg][tj * 16 + t16] = acc[ti][tj][rg];
        s8v o0, o1;
#pragma unroll
        for (int u = 0; u < 8; ++u) {
            o0[u] = (short)f2bf(epi[w][lr][c16 + u]     + bias[u >> 2][u & 3]);
            o1[u] = (short)f2bf(epi[w][lr][c16 + 8 + u] + bias[2 + (u >> 2)][u & 3]);
        }
        size_t orow = (size_t)(row0 + wm + ti * 16 + lr) * D_DIM + col0 + wn + c16;
        *(s8v*)&XE[orow]     = o0;
        *(s8v*)&XE[orow + 8] = o1;
    }
}

// ---------------------------------------------------------------------------
// k_step_mfma (x64): y = tanh(XE[b*L+t,:] + h_prev[b,:] @ Whh); XE[..] = bf16(y)
// 64x64 tile, 512 thr (8 waves = 2/SIMD), R7 loop + pad-40.
// Wave (wr,wc)=(w>>2,w&3): rows wr*32+[0,32), cols wc*16+[0,16).
// ---------------------------------------------------------------------------
__global__ __launch_bounds__(512) void k_step_mfma(
    const bf16_t* __restrict__ Abase, int strideRow,
    const bf16_t* __restrict__ WhhT, bf16_t* __restrict__ XE, int t)
{
    __shared__ bf16_t As[64 * LDA];            // 5 KB
    __shared__ bf16_t Bs[64 * LDA];            // 5 KB
    __shared__ float  epi[8][16][20];          // 10.2 KB (per-wave private)

    const int tid = threadIdx.x;
    const int w = tid >> 6, l = tid & 63;
    const int q = l >> 4, t16 = l & 15;
    const int wr = w >> 2, wc = w & 3;
    const int row0 = blockIdx.x * 64, col0 = blockIdx.y * 64;

    // R7 coalesced staging: 8 lanes cover 64 B of one row
    const int srow = tid >> 3, scol = (tid & 7) << 2;
    const bf16_t* asrc = Abase + (size_t)(row0 + srow) * strideRow + scol;
    const bf16_t* bsrc = WhhT + (size_t)(col0 + srow) * D_DIM + scol;

    f4v acc[2];
    acc[0] = (f4v)0.f; acc[1] = (f4v)0.f;

    s4v rA = *(const s4v*)(asrc);
    s4v rB = *(const s4v*)(bsrc);

    for (int k0 = 0; k0 < D_DIM; k0 += 32) {
        __syncthreads();
        *(s4v*)&As[srow * LDA + scol] = rA;
        *(s4v*)&Bs[srow * LDA + scol] = rB;
        int kn = k0 + 32;
        if (kn < D_DIM) {
            rA = *(const s4v*)(asrc + kn);
            rB = *(const s4v*)(bsrc + kn);
        }
        __syncthreads();
        s8v af[2], bfr;
#pragma unroll
        for (int ti = 0; ti < 2; ++ti)
            af[ti] = *(const s8v*)&As[(wr * 32 + ti * 16 + t16) * LDA + q * 8];
        bfr = *(const s8v*)&Bs[(wc * 16 + t16) * LDA + q * 8];
#pragma unroll
        for (int ti = 0; ti < 2; ++ti)
            acc[ti] = mfma16(af[ti], bfr, acc[ti]);
    }

    // per-wave epilogue, no barriers
    const int lr = l >> 2, c4 = (l & 3) * 4;
#pragma unroll
    for (int ti = 0; ti < 2; ++ti) {
#pragma unroll
        for (int rg = 0; rg < 4; ++rg)
            epi[w][q * 4 + rg][t16] = acc[ti][rg];
        f4v v = *(const f4v*)&epi[w][lr][c4];
        int b = row0 + wr * 32 + ti * 16 + lr;
        size_t xi = ((size_t)b * L_SEQ + t) * D_DIM + col0 + wc * 16 + c4;
        s4v x = *(const s4v*)&XE[xi];
        s4v o;
#pragma unroll
        for (int u = 0; u < 4; ++u)
            o[u] = (short)f2bf(fast_tanh(bf2f((unsigned short)x[u]) + v[u]));
        *(s4v*)&XE[xi] = o;
    }
}

// ---------------------------------------------------------------------------
// k_mlp_mfma: h = tanh(concat(XE[i],XE[j]) @ W1 + b1) fused with rule-dot.
// 128x128, K=2048, R9 two-barrier loop + prefetch, pad-40, XCD swizzle.
// ---------------------------------------------------------------------------
__global__ __launch_bounds__(256) void k_mlp_mfma(
    const int* __restrict__ i_idx, const int* __restrict__ j_idx,
    const bf16_t* __restrict__ XE, const bf16_t* __restrict__ W1T,
    const float* __restrict__ b1, const bf16_t* __restrict__ Wt2,
    const int* __restrict__ r_idx, float* __restrict__ partials)
{
    __shared__ bf16_t As[128 * LDA];           // 10 KB
    __shared__ bf16_t Bs[128 * LDA];           // 10 KB

    const int bi  = blockIdx.x;
    const int xcd = bi & 7, j = bi >> 3;
    const int rowTile = (xcd << 6) + (j >> 3);
    const int colTile = j & 7;
    const int row0 = rowTile * 128, col0 = colTile * 128;

    const int tid = threadIdx.x;
    const int w = tid >> 6, l = tid & 63;
    const int q = l >> 4, t16 = l & 15;
    const int wm = (w >> 1) * 64, wn = (w & 1) * 64;

    const int rr = tid >> 2, cc = (tid & 3) << 3;
    const bf16_t* pi[2]; const bf16_t* pj[2];
#pragma unroll
    for (int r = 0; r < 2; ++r) {
        int m = row0 + rr + r * 64;
        pi[r] = XE + (size_t)i_idx[m] * D_DIM + cc;
        pj[r] = XE + (size_t)j_idx[m] * D_DIM - D_DIM + cc;   // k in [1024,2048)
    }
    const bf16_t* brow[2];
#pragma unroll
    for (int r = 0; r < 2; ++r)
        brow[r] = W1T + (size_t)(col0 + rr + r * 64) * (2 * D_DIM) + cc;

    f4v acc[4][4];
#pragma unroll
    for (int i = 0; i < 4; ++i)
#pragma unroll
        for (int jj = 0; jj < 4; ++jj) acc[i][jj] = (f4v)0.f;

    // prefetch k=0
    s8v a0 = *(const s8v*)(pi[0]);
    s8v a1 = *(const s8v*)(pi[1]);
    s8v b0 = *(const s8v*)(brow[0]);
    s8v b1v = *(const s8v*)(brow[1]);

    for (int k0 = 0; k0 < 2 * D_DIM; k0 += 32) {
        __syncthreads();
        *(s8v*)&As[rr * LDA + cc]        = a0;
        *(s8v*)&As[(rr + 64) * LDA + cc] = a1;
        *(s8v*)&Bs[rr * LDA + cc]        = b0;
        *(s8v*)&Bs[(rr + 64) * LDA + cc] = b1v;
        int kn = k0 + 32;
        if (kn < 2 * D_DIM) {
            a0  = *(const s8v*)(((kn < D_DIM) ? pi[0] : pj[0]) + kn);
            a1  = *(const s8v*)(((kn < D_DIM) ? pi[1] : pj[1]) + kn);
            b0  = *(const s8v*)(brow[0] + kn);
            b1v = *(const s8v*)(brow[1] + kn);
        }
        __syncthreads();
        s8v af[4], bfr[4];
#pragma unroll
        for (int ti = 0; ti < 4; ++ti)
            af[ti] = *(const s8v*)&As[(wm + ti * 16 + t16) * LDA + q * 8];
#pragma unroll
        for (int tj = 0; tj < 4; ++tj)
            bfr[tj] = *(const s8v*)&Bs[(wn + tj * 16 + t16) * LDA + q * 8];
#pragma unroll
        for (int ti = 0; ti < 4; ++ti)
#pragma unroll
            for (int tj = 0; tj < 4; ++tj)
                acc[ti][tj] = mfma16(af[ti], bfr[tj], acc[ti][tj]);
    }

    // fused epilogue in C-layout: fast_tanh, dot with gathered rule row, 16-lane reduce
    const int cb = colTile * 2 + (w & 1);
#pragma unroll
    for (int ti = 0; ti < 4; ++ti) {
#pragma unroll
        for (int rg = 0; rg < 4; ++rg) {
            int m = row0 + wm + ti * 16 + q * 4 + rg;
            int r = r_idx[m];
            const bf16_t* wrow = Wt2 + (size_t)r * D_DIM + col0 + wn + t16;
            float pd = 0.f;
#pragma unroll
            for (int tj = 0; tj < 4; ++tj) {
                int col = col0 + wn + tj * 16 + t16;
                float h = fast_tanh(acc[ti][tj][rg] + b1[col]);
                pd += h * bf2f(wrow[tj * 16]);
            }
            pd += __shfl_xor(pd, 1);
            pd += __shfl_xor(pd, 2);
            pd += __shfl_xor(pd, 4);
            pd += __shfl_xor(pd, 8);
            if (t16 == 0)
                partials[(size_t)cb * M_NODES + m] = pd;
        }
    }
}

// ---------------------------------------------------------------------------
__global__ __launch_bounds__(256) void k_reduce(
    const float* __restrict__ partials, const int* __restrict__ r_idx,
    const float* __restrict__ b2, float* __restrict__ out)
{
    int m = blockIdx.x * 256 + threadIdx.x;
    float s = 0.f;
#pragma unroll
    for (int cb = 0; cb < 16; ++cb)
        s += partials[(size_t)cb * M_NODES + m];
    out[m] = s + b2[r_idx[m]];
}

// ---------------------------------------------------------------------------
extern "C" void kernel_launch(void* const* d_in, const int* in_sizes, int n_in,
                              void* d_out, int out_size, void* d_ws, size_t ws_size,
                              hipStream_t stream) {
    const int*   tokens = (const int*)  d_in[0];
    const int*   i_idx  = (const int*)  d_in[1];
    const int*   j_idx  = (const int*)  d_in[2];
    const int*   r_idx  = (const int*)  d_in[3];
    const float* emb    = (const float*)d_in[4];
    const float* Wxh    = (const float*)d_in[5];
    const float* Whh    = (const float*)d_in[6];
    const float* bh     = (const float*)d_in[7];
    const float* h0     = (const float*)d_in[8];
    const float* W1     = (const float*)d_in[9];
    const float* b1     = (const float*)d_in[10];
    const float* W2     = (const float*)d_in[11];
    const float* b2     = (const float*)d_in[12];
    float* out = (float*)d_out;

    // Workspace (~156 MiB). embB (20 MiB) aliases WhhT/W1T/Wt2 (22 MiB):
    // embB dead after k_xw_mfma; those conversions run after it.
    bf16_t* XE   = (bf16_t*)d_ws;                        // [B*L][D]  128 MiB
    bf16_t* WxhT = XE   + (size_t)M_NODES * D_DIM;       // [D][D]      2 MiB
    bf16_t* WhhT = WxhT + (size_t)D_DIM * D_DIM;         // [D][D]      2 MiB
    bf16_t* W1T  = WhhT + (size_t)D_DIM * D_DIM;         // [D][2D]     4 MiB
    bf16_t* Wt2  = W1T  + (size_t)2 * D_DIM * D_DIM;     // [R][D]     16 MiB
    bf16_t* embB = WhhT;                                 // [V][D]     20 MiB (alias)
    bf16_t* h0b  = Wt2  + (size_t)R_RULES * D_DIM;       // [D] (pad 2048)
    float*  par  = (float*)(h0b + 2048);                 // [16][M]     4 MiB

    // Phase 1: emb->bf16, Wxh, h0
    k_cvt_emb<<<V_VOCAB * D_DIM / 2048, 256, 0, stream>>>(emb, embB);
    k_transcvt<<<dim3(D_DIM / 32, D_DIM / 32), dim3(32, 8), 0, stream>>>(Wxh, WxhT, D_DIM, D_DIM);
    k_cvt_h0<<<1, 256, 0, stream>>>(h0, h0b);

    // Phase 2: XE = bf16(embB[tokens] @ Wxh + bh)   (last reader of embB)
    k_xw_mfma<<<4096, 256, 0, stream>>>(tokens, embB, WxhT, bh, XE);

    // Phase 3: remaining weight conversions (overwrite embB region)
    k_transcvt<<<dim3(D_DIM / 32, D_DIM / 32), dim3(32, 8), 0, stream>>>(Whh, WhhT, D_DIM, D_DIM);
    k_transcvt<<<dim3(D_DIM / 32, 2 * D_DIM / 32), dim3(32, 8), 0, stream>>>(W1, W1T, 2 * D_DIM, D_DIM);
    k_transcvt<<<dim3(R_RULES / 32, D_DIM / 32), dim3(32, 8), 0, stream>>>(W2, Wt2, D_DIM, R_RULES);

    // Phase 4: 64 sequential RNN steps (in-place on XE)
    for (int t = 0; t < L_SEQ; ++t) {
        const bf16_t* Abase = (t == 0) ? h0b : (XE + (size_t)(t - 1) * D_DIM);
        int strideRow       = (t == 0) ? 0   : L_SEQ * D_DIM;
        k_step_mfma<<<dim3(B_BATCH / 64, D_DIM / 64), 512, 0, stream>>>(
            Abase, strideRow, WhhT, XE, t);
    }

    // Phase 5: MLP + fused rule-dot partials
    k_mlp_mfma<<<4096, 256, 0, stream>>>(
        i_idx, j_idx, XE, W1T, b1, Wt2, r_idx, par);

    // Phase 6: deterministic reduce + b2
    k_reduce<<<M_NODES / 256, 256, 0, stream>>>(par, r_idx, b2, out);
}